// Round 20
// baseline (91.689 us; speedup 1.0000x reference)
//
#include <hip/hip_runtime.h>
#include <stdint.h>

#define NN 8192   // nodes
#define NE 8192   // edges
#define DIM 128
#define NL 17
#define SPLITK 8
#define KCHUNK (NN / SPLITK)   // 1024
#define NIT64 (KCHUNK / 64)    // 16 iterations of BK=64

typedef float f32x4 __attribute__((ext_vector_type(4)));
typedef short short8 __attribute__((ext_vector_type(8)));

// ---- workspace layout (bytes) ----
#define WS_XHI    0ull                              // 2 MB  (xT blocked bf16)
#define WS_COLSUM (4ull << 20)                      // 64 KB (128 x 128 f32)
#define WS_C0E    ((4ull << 20) + (64ull << 10))    // 8.5 KB
#define WS_WP     (5ull << 20)                      // 544 KB (17 x 64 x 128 u32)
#define WS_PART   (8ull << 20)                      // 16 MB (SPLITK x E x 64 u32, packed bf16 pairs)

#define GPTR(p) ((const __attribute__((address_space(1))) uint32_t*)(p))
#define LPTR(p) ((__attribute__((address_space(3))) uint32_t*)(p))

// Round-to-nearest-even f32 -> bf16 bits.
__device__ __forceinline__ uint16_t f32_to_bf16(float v) {
  uint32_t u = __builtin_bit_cast(uint32_t, v);
  u += 0x7fffu + ((u >> 16) & 1u);
  return (uint16_t)(u >> 16);
}

// Prep: column sums of x (for x0), and x transposed into k-blocked bf16:
// xhi[kblk][d][kk] with kblk = k/32, kk = k%32. 128 blocks x 64 nodes.
__global__ __launch_bounds__(256) void k_prep(const float* __restrict__ x,
                                              uint16_t* __restrict__ xhi,
                                              float* __restrict__ colsum) {
  __shared__ float xs[64][129];
  const int t = threadIdx.x;
  const int b = blockIdx.x;  // nodes b*64 .. b*64+63
  const float4* xg = (const float4*)(x + (size_t)b * 64 * DIM);
  for (int r = 0; r < 8; ++r) {
    int f = t + r * 256;           // float4 index within tile
    float4 v = xg[f];
    int n = f >> 5;
    int d0 = (f & 31) * 4;
    xs[n][d0] = v.x; xs[n][d0 + 1] = v.y; xs[n][d0 + 2] = v.z; xs[n][d0 + 3] = v.w;
  }
  __syncthreads();
  if (t < 128) {
    float s = 0.f;
    for (int n = 0; n < 64; ++n) s += xs[n][t];
    colsum[b * DIM + t] = s;
  }
  // 1024 16B chunks: q = [kb(1)][d(7)][c(2)]
  for (int r = 0; r < 4; ++r) {
    int q = t + r * 256;
    int c = q & 3;
    int d = (q >> 2) & 127;
    int kb = q >> 9;
    int kk0 = c * 8;
    uint32_t w[4];
    for (int j = 0; j < 4; ++j) {
      uint16_t h0 = f32_to_bf16(xs[kb * 32 + kk0 + 2 * j][d]);
      uint16_t h1 = f32_to_bf16(xs[kb * 32 + kk0 + 2 * j + 1][d]);
      w[j] = (uint32_t)h0 | ((uint32_t)h1 << 16);
    }
    int kblk = b * 2 + kb;
    uint16_t* dst = xhi + ((size_t)(kblk * 128 + d)) * 32 + kk0;
    *(uint4*)dst = make_uint4(w[0], w[1], w[2], w[3]);
  }
}

// Fused GEMM + aux. Blocks 0..1023: MFMA GEMM (BM=64, BK=64) writing
// packed-bf16 part16. Blocks 1024..1040: c0e[l]. Blocks 1041..1057: Wp[l].
// GEMM at 4 blocks/CU (launch_bounds(256,4)): 16 waves/CU to cover the
// HBM A-stream latency. T4 counted wait: vmcnt(20) keeps the just-issued
// next-iteration loads (4 stage + 16 A) in flight across the barrier.
__global__ __launch_bounds__(256, 4) void k_gemm(const float* __restrict__ inc,
                                                 const uint16_t* __restrict__ xhi,
                                                 uint32_t* __restrict__ part16,
                                                 const float* __restrict__ colsum,
                                                 const float* __restrict__ W,
                                                 const float* __restrict__ Bb,
                                                 float* __restrict__ c0e,
                                                 uint32_t* __restrict__ Wp) {
  __shared__ uint16_t Bs[2][8192];   // 16 KB per buffer (2 kblks), 32 KB
  const int t = threadIdx.x;

  if (blockIdx.x >= 1024) {
    const int bid2 = blockIdx.x - 1024;
    if (bid2 < 17) {
      __shared__ float x0[DIM];
      if (t < 128) {
        float s = 0.f;
        for (int b = 0; b < 128; ++b) s += colsum[b * DIM + t];
        x0[t] = s * (1.0f / NN);
      }
      __syncthreads();
      if (t < 128) {
        const int l = bid2;
        const float* W0l = W + (size_t)l * DIM * DIM;
        float acc = Bb[l * DIM + t];
#pragma unroll 8
        for (int i = 0; i < DIM; ++i) acc += x0[i] * W0l[(size_t)i * DIM + t];
        c0e[l * DIM + t] = acc;
      }
    } else {
      const int l = bid2 - 17;
      const int j = t & 127;
      const int half = t >> 7;
      const float* W1l = W + (size_t)(NL + l) * DIM * DIM;
      uint32_t* dst = Wp + (size_t)l * 64 * DIM;
#pragma unroll 8
      for (int q = 0; q < 32; ++q) {
        int i2 = half * 32 + q;
        uint16_t lo = f32_to_bf16(W1l[(size_t)(2 * i2) * DIM + j]);
        uint16_t hi = f32_to_bf16(W1l[(size_t)(2 * i2 + 1) * DIM + j]);
        dst[i2 * DIM + j] = (uint32_t)lo | ((uint32_t)hi << 16);
      }
    }
    return;
  }

  const int mb = blockIdx.x & 127;   // 128 M-tiles of 64 edges
  const int s = blockIdx.x >> 7;     // 8 splits
  const int e0 = mb * 64;
  const int w = t >> 6;
  const int lane = t & 63;
  const int lm = lane & 15;
  const int lk = lane >> 4;          // 0..3
  const int kbase = s * KCHUNK;
  const int kb0 = kbase >> 5;        // first kblk

  f32x4 acc[8];
#pragma unroll
  for (int b = 0; b < 8; ++b) acc[b] = (f32x4){0.f, 0.f, 0.f, 0.f};

  const char* hbase = (const char*)xhi;

#define STAGE(buf, it) { \
    const char* hsrc = hbase + (size_t)(kb0 + 2 * (it)) * 8192; \
    char* dbase = (char*)&Bs[buf][0]; \
    _Pragma("unroll") \
    for (int j = 0; j < 4; ++j) { \
      int q = w + 4 * j; \
      __builtin_amdgcn_global_load_lds(GPTR(hsrc + q * 1024 + lane * 16), \
                                       LPTR(dbase + q * 1024), 16, 0, 0); \
    } }

#define LOADA(u, it) { \
    _Pragma("unroll") \
    for (int kh = 0; kh < 2; ++kh) { \
      const int k0_ = kbase + (it) * 64 + kh * 32; \
      const float* ap = inc + (size_t)(k0_ + lk * 8) * NE + (e0 + w * 16 + lm); \
      _Pragma("unroll") \
      for (int j = 0; j < 8; ++j) \
        u[kh * 8 + j] = __builtin_bit_cast(uint32_t, ap[(size_t)j * NE]); \
    } }

#define COMPUTE(buf, u) { \
    _Pragma("unroll") \
    for (int kh = 0; kh < 2; ++kh) { \
      short8 afr; \
      { \
        union { uint32_t w4[4]; short8 s8; } pk; \
        _Pragma("unroll") \
        for (int j = 0; j < 4; ++j) \
          pk.w4[j] = (u[kh * 8 + 2 * j + 1] & 0xffff0000u) | \
                     (u[kh * 8 + 2 * j] >> 16); \
        afr = pk.s8; \
      } \
      _Pragma("unroll") \
      for (int fn = 0; fn < 8; ++fn) { \
        int n = fn * 16 + lm; \
        short8 bh = *(const short8*)&Bs[buf][kh * 4096 + n * 32 + lk * 8]; \
        acc[fn] = __builtin_amdgcn_mfma_f32_16x16x32_bf16(afr, bh, acc[fn], 0, 0, 0); \
      } \
    } }

#define BAR() __builtin_amdgcn_s_barrier()
#define WAITK() { asm volatile("s_waitcnt vmcnt(20)" ::: "memory"); \
                  __builtin_amdgcn_sched_barrier(0); }
#define WAIT0() { asm volatile("s_waitcnt vmcnt(0)" ::: "memory"); \
                  __builtin_amdgcn_sched_barrier(0); }

  uint32_t ua[16], ub[16];
  STAGE(0, 0);
  LOADA(ua, 0);

  for (int it2 = 0; it2 < NIT64; it2 += 2) {
    if (it2 + 1 < NIT64) { STAGE(1, it2 + 1); LOADA(ub, it2 + 1); WAITK(); }
    else { WAIT0(); }
    BAR();
    COMPUTE(0, ua);
    BAR();
    if (it2 + 2 < NIT64) { STAGE(0, it2 + 2); LOADA(ua, it2 + 2); WAITK(); }
    else { WAIT0(); }
    BAR();
    COMPUTE(1, ub);
    BAR();
  }

  // epilogue: pack fn-pairs to bf16 u32, permuted slot u = j*16+lm
  uint32_t* pbase = part16 + (size_t)s * NE * 64;
#pragma unroll
  for (int r = 0; r < 4; ++r) {
    int e = e0 + w * 16 + lk * 4 + r;
#pragma unroll
    for (int j = 0; j < 4; ++j) {
      uint32_t pv = (uint32_t)f32_to_bf16(acc[2 * j][r]) |
                    ((uint32_t)f32_to_bf16(acc[2 * j + 1][r]) << 16);
      pbase[(size_t)e * 64 + j * 16 + lm] = pv;
    }
  }
#undef STAGE
#undef LOADA
#undef COMPUTE
#undef BAR
#undef WAITK
#undef WAIT0
}

// Fused edge + node kernel (128 threads).
// Blocks 0..8191: per-edge split-K reduce (packed bf16 partials), /norm,
// packed-bf16 W matvec + c0e -> out_e.  Blocks 8192..8703: node side,
// 16 rows each: out_v[n] = c0e[1] + x[n] @ W[1,1].
__global__ __launch_bounds__(128) void k_edgenode(const uint32_t* __restrict__ part16,
                                                  const int* __restrict__ orders,
                                                  const float* __restrict__ norm,
                                                  const uint32_t* __restrict__ Wp,
                                                  const float* __restrict__ c0e,
                                                  const float* __restrict__ x,
                                                  const float* __restrict__ W,
                                                  float* __restrict__ out_e,
                                                  float* __restrict__ out_v) {
  __shared__ float sh[16 * DIM];     // edge: xl[128]; node: xr[16][128]
  const int t = threadIdx.x;
  if (blockIdx.x < NE) {
    const int e = blockIdx.x;
    if (t < 64) {
      const int d0 = 32 * (t >> 4) + (t & 15);
      float s0 = 0.f, s1 = 0.f;
#pragma unroll
      for (int k = 0; k < SPLITK; ++k) {
        uint32_t v = part16[((size_t)k * NE + e) * 64 + t];
        s0 += __builtin_bit_cast(float, v << 16);
        s1 += __builtin_bit_cast(float, v & 0xffff0000u);
      }
      const float rn = norm[e];
      sh[d0] = s0 / rn;
      sh[d0 + 16] = s1 / rn;
    }
    __syncthreads();
    const int l = orders[e];
    const uint32_t* Wl = Wp + (size_t)l * 64 * DIM;
    float o = c0e[l * DIM + t];
#pragma unroll 8
    for (int i2 = 0; i2 < 64; ++i2) {
      uint32_t wv = Wl[i2 * DIM + t];
      float wlo = __builtin_bit_cast(float, wv << 16);
      float whi = __builtin_bit_cast(float, wv & 0xffff0000u);
      o += sh[2 * i2] * wlo;
      o += sh[2 * i2 + 1] * whi;
    }
    out_e[(size_t)e * DIM + t] = o;
  } else {
    const int nb = blockIdx.x - NE;       // 0..511
    const int row0 = nb * 16;
    {
      const float4* xg = (const float4*)(x + (size_t)row0 * DIM);
      float4* sh4 = (float4*)sh;
#pragma unroll
      for (int r = 0; r < 4; ++r) sh4[t + r * 128] = xg[t + r * 128];
    }
    const int tx = t & 31;
    const int ty = t >> 5;                // 0..3 -> rows ty*4..ty*4+3
    const float4* W4 = (const float4*)(W + (size_t)(NL + 1) * DIM * DIM);
    const float4 cv = ((const float4*)(c0e + DIM))[tx];
    float4 o0 = cv, o1 = cv, o2 = cv, o3 = cv;
    __syncthreads();
#pragma unroll 4
    for (int k = 0; k < DIM; ++k) {
      float4 w = W4[k * 32 + tx];
      float a0 = sh[(ty * 4 + 0) * DIM + k];
      float a1 = sh[(ty * 4 + 1) * DIM + k];
      float a2 = sh[(ty * 4 + 2) * DIM + k];
      float a3 = sh[(ty * 4 + 3) * DIM + k];
      o0.x += a0 * w.x; o0.y += a0 * w.y; o0.z += a0 * w.z; o0.w += a0 * w.w;
      o1.x += a1 * w.x; o1.y += a1 * w.y; o1.z += a1 * w.z; o1.w += a1 * w.w;
      o2.x += a2 * w.x; o2.y += a2 * w.y; o2.z += a2 * w.z; o2.w += a2 * w.w;
      o3.x += a3 * w.x; o3.y += a3 * w.y; o3.z += a3 * w.z; o3.w += a3 * w.w;
    }
    float4* out4 = (float4*)(out_v + (size_t)(row0 + ty * 4) * DIM);
    out4[0 * 32 + tx] = o0;
    out4[1 * 32 + tx] = o1;
    out4[2 * 32 + tx] = o2;
    out4[3 * 32 + tx] = o3;
  }
}

extern "C" void kernel_launch(void* const* d_in, const int* in_sizes, int n_in,
                              void* d_out, int out_size, void* d_ws, size_t ws_size,
                              hipStream_t stream) {
  const float* x      = (const float*)d_in[0];
  const float* inc    = (const float*)d_in[1];
  const int*   orders = (const int*)d_in[2];
  const float* norm   = (const float*)d_in[3];
  const float* W      = (const float*)d_in[4];
  const float* Bb     = (const float*)d_in[5];
  float* out_v = (float*)d_out;
  float* out_e = (float*)d_out + (size_t)NN * DIM;

  char* ws = (char*)d_ws;
  uint16_t* xhi    = (uint16_t*)(ws + WS_XHI);
  float* colsum    = (float*)(ws + WS_COLSUM);
  float* c0e       = (float*)(ws + WS_C0E);
  uint32_t* Wp     = (uint32_t*)(ws + WS_WP);
  uint32_t* part16 = (uint32_t*)(ws + WS_PART);

  k_prep<<<128, 256, 0, stream>>>(x, xhi, colsum);
  k_gemm<<<1024 + 34, 256, 0, stream>>>(inc, xhi, part16, colsum, W, Bb, c0e, Wp);
  k_edgenode<<<NE + 512, 128, 0, stream>>>(part16, orders, norm, Wp, c0e, x, W,
                                           out_e, out_v);
}

// Round 21
// 80.896 us; speedup vs baseline: 1.1334x; 1.1334x over previous
//
#include <hip/hip_runtime.h>
#include <stdint.h>

#define NN 8192   // nodes
#define NE 8192   // edges
#define DIM 128
#define NL 17
#define SPLITK 8
#define KCHUNK (NN / SPLITK)   // 1024
#define NIT64 (KCHUNK / 64)    // 16 iterations of BK=64

typedef float f32x4 __attribute__((ext_vector_type(4)));
typedef short short8 __attribute__((ext_vector_type(8)));

// ---- workspace layout (bytes) ----
#define WS_XHI    0ull                              // 2 MB  (xT blocked bf16)
#define WS_COLSUM (4ull << 20)                      // 64 KB (128 x 128 f32)
#define WS_C0E    ((4ull << 20) + (64ull << 10))    // 8.5 KB
#define WS_WP     (5ull << 20)                      // 544 KB (17 x 64 x 128 u32)
#define WS_PART   (8ull << 20)                      // 16 MB (SPLITK x E x 64 u32, packed bf16 pairs)

#define GPTR(p) ((const __attribute__((address_space(1))) uint32_t*)(p))
#define LPTR(p) ((__attribute__((address_space(3))) uint32_t*)(p))

// Round-to-nearest-even f32 -> bf16 bits.
__device__ __forceinline__ uint16_t f32_to_bf16(float v) {
  uint32_t u = __builtin_bit_cast(uint32_t, v);
  u += 0x7fffu + ((u >> 16) & 1u);
  return (uint16_t)(u >> 16);
}

// Prep: column sums of x (for x0), and x transposed into k-blocked bf16:
// xhi[kblk][d][kk] with kblk = k/32, kk = k%32. 128 blocks x 64 nodes.
__global__ __launch_bounds__(256) void k_prep(const float* __restrict__ x,
                                              uint16_t* __restrict__ xhi,
                                              float* __restrict__ colsum) {
  __shared__ float xs[64][129];
  const int t = threadIdx.x;
  const int b = blockIdx.x;  // nodes b*64 .. b*64+63
  const float4* xg = (const float4*)(x + (size_t)b * 64 * DIM);
  for (int r = 0; r < 8; ++r) {
    int f = t + r * 256;           // float4 index within tile
    float4 v = xg[f];
    int n = f >> 5;
    int d0 = (f & 31) * 4;
    xs[n][d0] = v.x; xs[n][d0 + 1] = v.y; xs[n][d0 + 2] = v.z; xs[n][d0 + 3] = v.w;
  }
  __syncthreads();
  if (t < 128) {
    float s = 0.f;
    for (int n = 0; n < 64; ++n) s += xs[n][t];
    colsum[b * DIM + t] = s;
  }
  // 1024 16B chunks: q = [kb(1)][d(7)][c(2)]
  for (int r = 0; r < 4; ++r) {
    int q = t + r * 256;
    int c = q & 3;
    int d = (q >> 2) & 127;
    int kb = q >> 9;
    int kk0 = c * 8;
    uint32_t w[4];
    for (int j = 0; j < 4; ++j) {
      uint16_t h0 = f32_to_bf16(xs[kb * 32 + kk0 + 2 * j][d]);
      uint16_t h1 = f32_to_bf16(xs[kb * 32 + kk0 + 2 * j + 1][d]);
      w[j] = (uint32_t)h0 | ((uint32_t)h1 << 16);
    }
    int kblk = b * 2 + kb;
    uint16_t* dst = xhi + ((size_t)(kblk * 128 + d)) * 32 + kk0;
    *(uint4*)dst = make_uint4(w[0], w[1], w[2], w[3]);
  }
}

// Fused GEMM + aux (R18 geometry, aux FRONT-LOADED). Blocks 0..16: c0e[l].
// Blocks 17..33: Wp[l] packed-bf16 W[1][l]. Blocks 34..545: MFMA GEMM
// (BM=128, BK=64, SPLITK=8) writing packed-bf16 part16. Aux at the FRONT
// runs concurrently with the first gemm dispatch wave instead of as a
// serialized tail (colsum/W deps satisfied by the prior k_prep launch).
// T4 counted wait: vmcnt(36) keeps the just-issued next-iteration loads
// (4 stage + 32 A) in flight across the barrier.
__global__ __launch_bounds__(256, 2) void k_gemm(const float* __restrict__ inc,
                                                 const uint16_t* __restrict__ xhi,
                                                 uint32_t* __restrict__ part16,
                                                 const float* __restrict__ colsum,
                                                 const float* __restrict__ W,
                                                 const float* __restrict__ Bb,
                                                 float* __restrict__ c0e,
                                                 uint32_t* __restrict__ Wp) {
  __shared__ uint16_t Bs[2][8192];   // 16 KB per buffer (2 kblks)
  const int t = threadIdx.x;

  if (blockIdx.x < 34) {
    const int bid2 = blockIdx.x;
    if (bid2 < 17) {
      __shared__ float x0[DIM];
      if (t < 128) {
        float s = 0.f;
        for (int b = 0; b < 128; ++b) s += colsum[b * DIM + t];
        x0[t] = s * (1.0f / NN);
      }
      __syncthreads();
      if (t < 128) {
        const int l = bid2;
        const float* W0l = W + (size_t)l * DIM * DIM;
        float acc = Bb[l * DIM + t];
#pragma unroll 8
        for (int i = 0; i < DIM; ++i) acc += x0[i] * W0l[(size_t)i * DIM + t];
        c0e[l * DIM + t] = acc;
      }
    } else {
      const int l = bid2 - 17;
      const int j = t & 127;
      const int half = t >> 7;
      const float* W1l = W + (size_t)(NL + l) * DIM * DIM;
      uint32_t* dst = Wp + (size_t)l * 64 * DIM;
#pragma unroll 8
      for (int q = 0; q < 32; ++q) {
        int i2 = half * 32 + q;
        uint16_t lo = f32_to_bf16(W1l[(size_t)(2 * i2) * DIM + j]);
        uint16_t hi = f32_to_bf16(W1l[(size_t)(2 * i2 + 1) * DIM + j]);
        dst[i2 * DIM + j] = (uint32_t)lo | ((uint32_t)hi << 16);
      }
    }
    return;
  }

  const int bid = blockIdx.x - 34;
  const int mb = bid & 63;
  const int s = bid >> 6;
  const int e0 = mb * 128;
  const int w = t >> 6;
  const int lane = t & 63;
  const int lm = lane & 15;
  const int lk = lane >> 4;          // 0..3
  const int kbase = s * KCHUNK;
  const int kb0 = kbase >> 5;        // first kblk

  f32x4 acc[2][8];
#pragma unroll
  for (int a = 0; a < 2; ++a)
#pragma unroll
    for (int b = 0; b < 8; ++b) acc[a][b] = (f32x4){0.f, 0.f, 0.f, 0.f};

  const char* hbase = (const char*)xhi;

#define STAGE(buf, it) { \
    const char* hsrc = hbase + (size_t)(kb0 + 2 * (it)) * 8192; \
    char* dbase = (char*)&Bs[buf][0]; \
    _Pragma("unroll") \
    for (int j = 0; j < 4; ++j) { \
      int q = w + 4 * j; \
      __builtin_amdgcn_global_load_lds(GPTR(hsrc + q * 1024 + lane * 16), \
                                       LPTR(dbase + q * 1024), 16, 0, 0); \
    } }

#define LOADA(u, it) { \
    _Pragma("unroll") \
    for (int kh = 0; kh < 2; ++kh) { \
      const int k0_ = kbase + (it) * 64 + kh * 32; \
      _Pragma("unroll") \
      for (int fm = 0; fm < 2; ++fm) { \
        const float* ap = inc + (size_t)(k0_ + lk * 8) * NE + (e0 + w * 32 + fm * 16 + lm); \
        _Pragma("unroll") \
        for (int j = 0; j < 8; ++j) \
          u[fm][kh * 8 + j] = __builtin_bit_cast(uint32_t, ap[(size_t)j * NE]); \
      } \
    } }

#define COMPUTE(buf, u) { \
    _Pragma("unroll") \
    for (int kh = 0; kh < 2; ++kh) { \
      short8 afr[2]; \
      _Pragma("unroll") \
      for (int fm = 0; fm < 2; ++fm) { \
        union { uint32_t w4[4]; short8 s8; } pk; \
        _Pragma("unroll") \
        for (int j = 0; j < 4; ++j) \
          pk.w4[j] = (u[fm][kh * 8 + 2 * j + 1] & 0xffff0000u) | \
                     (u[fm][kh * 8 + 2 * j] >> 16); \
        afr[fm] = pk.s8; \
      } \
      _Pragma("unroll") \
      for (int fn = 0; fn < 8; ++fn) { \
        int n = fn * 16 + lm; \
        short8 bh = *(const short8*)&Bs[buf][kh * 4096 + n * 32 + lk * 8]; \
        acc[0][fn] = __builtin_amdgcn_mfma_f32_16x16x32_bf16(afr[0], bh, acc[0][fn], 0, 0, 0); \
        acc[1][fn] = __builtin_amdgcn_mfma_f32_16x16x32_bf16(afr[1], bh, acc[1][fn], 0, 0, 0); \
      } \
    } }

#define BAR() __builtin_amdgcn_s_barrier()
#define WAITK() { asm volatile("s_waitcnt vmcnt(36)" ::: "memory"); \
                  __builtin_amdgcn_sched_barrier(0); }
#define WAIT0() { asm volatile("s_waitcnt vmcnt(0)" ::: "memory"); \
                  __builtin_amdgcn_sched_barrier(0); }

  uint32_t ua[2][16], ub[2][16];
  STAGE(0, 0);
  LOADA(ua, 0);

  for (int it2 = 0; it2 < NIT64; it2 += 2) {
    if (it2 + 1 < NIT64) { STAGE(1, it2 + 1); LOADA(ub, it2 + 1); WAITK(); }
    else { WAIT0(); }
    BAR();
    COMPUTE(0, ua);
    BAR();
    if (it2 + 2 < NIT64) { STAGE(0, it2 + 2); LOADA(ua, it2 + 2); WAITK(); }
    else { WAIT0(); }
    BAR();
    COMPUTE(1, ub);
    BAR();
  }

  // epilogue: pack fn-pairs to bf16 u32, permuted slot u = j*16+lm
  uint32_t* pbase = part16 + (size_t)s * NE * 64;
#pragma unroll
  for (int fm = 0; fm < 2; ++fm)
#pragma unroll
    for (int r = 0; r < 4; ++r) {
      int e = e0 + w * 32 + fm * 16 + lk * 4 + r;
#pragma unroll
      for (int j = 0; j < 4; ++j) {
        uint32_t pv = (uint32_t)f32_to_bf16(acc[fm][2 * j][r]) |
                      ((uint32_t)f32_to_bf16(acc[fm][2 * j + 1][r]) << 16);
        pbase[(size_t)e * 64 + j * 16 + lm] = pv;
      }
    }
#undef STAGE
#undef LOADA
#undef COMPUTE
#undef BAR
#undef WAITK
#undef WAIT0
}

// Fused edge + node kernel (128 threads), node FRONT-LOADED.
// Blocks 0..511: node side, 16 rows each: out_v[n] = c0e[1] + x[n]@W[1,1].
// Blocks 512..8703: per-edge split-K reduce (packed bf16 partials), /norm,
// packed-bf16 W matvec + c0e -> out_e.
__global__ __launch_bounds__(128) void k_edgenode(const uint32_t* __restrict__ part16,
                                                  const int* __restrict__ orders,
                                                  const float* __restrict__ norm,
                                                  const uint32_t* __restrict__ Wp,
                                                  const float* __restrict__ c0e,
                                                  const float* __restrict__ x,
                                                  const float* __restrict__ W,
                                                  float* __restrict__ out_e,
                                                  float* __restrict__ out_v) {
  __shared__ float sh[16 * DIM];     // edge: xl[128]; node: xr[16][128]
  const int t = threadIdx.x;
  if (blockIdx.x >= 512) {
    const int e = blockIdx.x - 512;
    if (t < 64) {
      const int d0 = 32 * (t >> 4) + (t & 15);
      float s0 = 0.f, s1 = 0.f;
#pragma unroll
      for (int k = 0; k < SPLITK; ++k) {
        uint32_t v = part16[((size_t)k * NE + e) * 64 + t];
        s0 += __builtin_bit_cast(float, v << 16);
        s1 += __builtin_bit_cast(float, v & 0xffff0000u);
      }
      const float rn = norm[e];
      sh[d0] = s0 / rn;
      sh[d0 + 16] = s1 / rn;
    }
    __syncthreads();
    const int l = orders[e];
    const uint32_t* Wl = Wp + (size_t)l * 64 * DIM;
    float o = c0e[l * DIM + t];
#pragma unroll 8
    for (int i2 = 0; i2 < 64; ++i2) {
      uint32_t wv = Wl[i2 * DIM + t];
      float wlo = __builtin_bit_cast(float, wv << 16);
      float whi = __builtin_bit_cast(float, wv & 0xffff0000u);
      o += sh[2 * i2] * wlo;
      o += sh[2 * i2 + 1] * whi;
    }
    out_e[(size_t)e * DIM + t] = o;
  } else {
    const int nb = blockIdx.x;            // 0..511
    const int row0 = nb * 16;
    {
      const float4* xg = (const float4*)(x + (size_t)row0 * DIM);
      float4* sh4 = (float4*)sh;
#pragma unroll
      for (int r = 0; r < 4; ++r) sh4[t + r * 128] = xg[t + r * 128];
    }
    const int tx = t & 31;
    const int ty = t >> 5;                // 0..3 -> rows ty*4..ty*4+3
    const float4* W4 = (const float4*)(W + (size_t)(NL + 1) * DIM * DIM);
    const float4 cv = ((const float4*)(c0e + DIM))[tx];
    float4 o0 = cv, o1 = cv, o2 = cv, o3 = cv;
    __syncthreads();
#pragma unroll 4
    for (int k = 0; k < DIM; ++k) {
      float4 w = W4[k * 32 + tx];
      float a0 = sh[(ty * 4 + 0) * DIM + k];
      float a1 = sh[(ty * 4 + 1) * DIM + k];
      float a2 = sh[(ty * 4 + 2) * DIM + k];
      float a3 = sh[(ty * 4 + 3) * DIM + k];
      o0.x += a0 * w.x; o0.y += a0 * w.y; o0.z += a0 * w.z; o0.w += a0 * w.w;
      o1.x += a1 * w.x; o1.y += a1 * w.y; o1.z += a1 * w.z; o1.w += a1 * w.w;
      o2.x += a2 * w.x; o2.y += a2 * w.y; o2.z += a2 * w.z; o2.w += a2 * w.w;
      o3.x += a3 * w.x; o3.y += a3 * w.y; o3.z += a3 * w.z; o3.w += a3 * w.w;
    }
    float4* out4 = (float4*)(out_v + (size_t)(row0 + ty * 4) * DIM);
    out4[0 * 32 + tx] = o0;
    out4[1 * 32 + tx] = o1;
    out4[2 * 32 + tx] = o2;
    out4[3 * 32 + tx] = o3;
  }
}

extern "C" void kernel_launch(void* const* d_in, const int* in_sizes, int n_in,
                              void* d_out, int out_size, void* d_ws, size_t ws_size,
                              hipStream_t stream) {
  const float* x      = (const float*)d_in[0];
  const float* inc    = (const float*)d_in[1];
  const int*   orders = (const int*)d_in[2];
  const float* norm   = (const float*)d_in[3];
  const float* W      = (const float*)d_in[4];
  const float* Bb     = (const float*)d_in[5];
  float* out_v = (float*)d_out;
  float* out_e = (float*)d_out + (size_t)NN * DIM;

  char* ws = (char*)d_ws;
  uint16_t* xhi    = (uint16_t*)(ws + WS_XHI);
  float* colsum    = (float*)(ws + WS_COLSUM);
  float* c0e       = (float*)(ws + WS_C0E);
  uint32_t* Wp     = (uint32_t*)(ws + WS_WP);
  uint32_t* part16 = (uint32_t*)(ws + WS_PART);

  k_prep<<<128, 256, 0, stream>>>(x, xhi, colsum);
  k_gemm<<<546, 256, 0, stream>>>(inc, xhi, part16, colsum, W, Bb, c0e, Wp);
  k_edgenode<<<NE + 512, 128, 0, stream>>>(part16, orders, norm, Wp, c0e, x, W,
                                           out_e, out_v);
}